// Round 7
// baseline (1926.096 us; speedup 1.0000x reference)
//
#include <hip/hip_runtime.h>

// VQProsodyEncoder on gfx950: 13x conv1d(K=5) as implicit-GEMM f16 MFMA,
// maxpool(8), VQ via (-2*z.c + |c|^2) GEMM + fused partial argmin + gather.
// Activations: channel-last f16 [B][T+4][C] with 2-row zero halos.
// R8 = R7 (verified 112us big-conv: 128x128 tile, frag-major A in LDS,
// 0 bank conflicts, fused VQ argmin) + B BYPASSES LDS ENTIRELY: per-lane
// global loads straight into MFMA B-fragments (lane pattern row=j*16+r16+kt,
// k=g4*8 covers whole 64B lines -> fully coalesced; no intra-wave reuse
// existed, so LDS bought nothing for B). Halves LDS read traffic (R7's top
// pipe at ~62%), removes B staging writes, and the per-c32 barrier drain now
// waits only on L2-resident A (~300cy), never on HBM-latency B. LDS 50->40KB.

typedef _Float16 f16;
typedef __attribute__((ext_vector_type(8))) _Float16 half8;
typedef __attribute__((ext_vector_type(4))) _Float16 half4;
typedef __attribute__((ext_vector_type(4))) float float4v;

__device__ __forceinline__ void async16(const void* g, void* l) {
  __builtin_amdgcn_global_load_lds(
      (const __attribute__((address_space(1))) void*)g,
      (__attribute__((address_space(3))) void*)l, 16, 0, 0);
}

// ---------------------------------------------------------------------------
// conv as implicit GEMM: Y[b,t,o] = sum_{kt,ci} W[kt][o][ci] * X[b][t+kt-2][ci]
// tile 128(M=o) x 128(N=b*t), BK=32, 4 waves 64x64, mfma_f32_16x16x32_f16.
// Wf is fragment-major: [NTAP][Cinp/32][Cout/16][64 lanes][8 f16].
template <int NTAP>
__global__ __launch_bounds__(256, 3) void conv_gemm(
    const f16* __restrict__ Xb,   // [B][T+4][Cinp], halo rows zeroed
    const f16* __restrict__ Wf,   // fragment-major weights
    const float* __restrict__ bias,  // [Cout]
    const f16* __restrict__ Res,  // [B][T+4][Cout] or null (residual add)
    float* __restrict__ Yf,       // [B][T][Cout] or null
    f16* __restrict__ Yb,         // [B][T+4][Cout] or null
    float2* __restrict__ Pmin,    // [N][gridDim.y] per-tile argmin or null
    int Cinp, int Cout, int lgT, int tapshift, int relu)
{
  __shared__ __align__(16) f16 Als[NTAP * 8 * 512];  // frag-major A: 8KB/tap

  const int tid  = threadIdx.x;
  const int wave = tid >> 6;
  const int lane = tid & 63;
  const int T  = 1 << lgT;
  const int n0 = blockIdx.x << 7;
  const int o0 = blockIdx.y << 7;
  const int b  = n0 >> lgT;
  const int t0 = n0 & (T - 1);

  const int mB  = (wave & 1) * 64;
  const int nB  = (wave >> 1) * 64;
  const int r16 = lane & 15;
  const int g4  = lane >> 4;        // k-slot (8 f16) of this lane
  const int C32 = Cinp >> 5;
  const int OB  = Cout >> 4;
  const int fb  = (wave & 1) * 4;   // first A-frag within a tap's 8

  // fragment-major W: frag index (kt*C32+c32)*OB + ob, each frag 512 f16.
  const f16* gW = Wf + (((size_t)(o0 >> 4)) << 9) + lane * 8;
  // B per-lane base: row (halo coords) = t0 + nB + tapshift + r16, k = g4*8.
  const f16* gBr = Xb + ((size_t)(b * (T + 4) + t0 + nB + tapshift + r16)) * Cinp
                      + g4 * 8;

  float4v acc[4][4] = {};

#pragma unroll 1
  for (int c32 = 0; c32 < C32; ++c32) {
    __syncthreads();  // previous iteration's LDS reads complete (WAR)
    // stage A: NTAP*8 frags of 1KB (frag-major, linear -> conflict-free)
#pragma unroll
    for (int r = wave; r < NTAP * 8; r += 4) {
      const int kt = r >> 3, frag = r & 7;
      async16(gW + (((size_t)((kt * C32 + c32) * OB) + frag) << 9),
              &Als[r * 512 + lane * 8]);
    }
    __syncthreads();  // drains vmcnt: A staging visible (L2, ~300cy)

    // B fragments: direct per-lane global loads, all issued up front; the
    // compiler inserts counted waits before first use (G7) so L3/HBM
    // latency hides under tap-0..k MFMA.
    half8 bq[NTAP][4];
#pragma unroll
    for (int kt = 0; kt < NTAP; ++kt)
#pragma unroll
      for (int j = 0; j < 4; ++j)
        bq[kt][j] = *(const half8*)(gBr + (size_t)(j * 16 + kt) * Cinp
                                        + (c32 << 5));

#pragma unroll
    for (int kt = 0; kt < NTAP; ++kt) {
      half8 af[4];
#pragma unroll
      for (int i = 0; i < 4; ++i)
        af[i] = *(const half8*)&Als[(kt * 8 + fb + i) * 512 + lane * 8];
      __builtin_amdgcn_s_setprio(1);
#pragma unroll
      for (int i = 0; i < 4; ++i)
#pragma unroll
        for (int j = 0; j < 4; ++j)
          acc[i][j] = __builtin_amdgcn_mfma_f32_16x16x32_f16(af[i], bq[kt][j], acc[i][j], 0, 0, 0);
      __builtin_amdgcn_s_setprio(0);
    }
  }

  // epilogue: D[row][col]: col = lane&15, row = (lane>>4)*4 + reg
  const int col = lane & 15;
  const int qr4 = (lane >> 4) << 2;

  if (Pmin) {
    // VQ path: per-row argmin over this block's 128 bins (o0..o0+127).
    float bv[4] = {3.4e38f, 3.4e38f, 3.4e38f, 3.4e38f};
    int   bi[4] = {0, 0, 0, 0};
#pragma unroll
    for (int i = 0; i < 4; ++i) {
      const int o = o0 + mB + i * 16 + qr4;
      const float4v bb = *(const float4v*)&bias[o];  // |c|^2
#pragma unroll
      for (int j = 0; j < 4; ++j) {
        float4v v = acc[i][j] + bb;
#pragma unroll
        for (int r = 0; r < 4; ++r) {
          const float f = v[r];
          const int id = o + r;
          if (f < bv[j] || (f == bv[j] && id < bi[j])) { bv[j] = f; bi[j] = id; }
        }
      }
    }
#pragma unroll
    for (int off = 32; off >= 16; off >>= 1)
#pragma unroll
      for (int j = 0; j < 4; ++j) {
        const float ov = __shfl_down(bv[j], off);
        const int   oi = __shfl_down(bi[j], off);
        if (ov < bv[j] || (ov == bv[j] && oi < bi[j])) { bv[j] = ov; bi[j] = oi; }
      }
    __syncthreads();  // all waves done with LDS -> reuse Als for candidates
    float2* cand = (float2*)Als;  // [128 t][2 m-waves]
    if (lane < 16)
#pragma unroll
      for (int j = 0; j < 4; ++j)
        cand[(nB + j * 16 + lane) * 2 + (wave & 1)] =
            make_float2(bv[j], __int_as_float(bi[j]));
    __syncthreads();
    if (tid < 128) {
      float2 c0 = cand[tid * 2 + 0], c1 = cand[tid * 2 + 1];
      int i0 = __float_as_int(c0.x < c1.x ? c0.y : c1.y);
      float v0 = fminf(c0.x, c1.x);
      if (c0.x == c1.x) i0 = min(__float_as_int(c0.y), __float_as_int(c1.y));
      Pmin[(size_t)(n0 + tid) * gridDim.y + blockIdx.y] =
          make_float2(v0, __int_as_float(i0));
    }
    return;
  }

#pragma unroll
  for (int i = 0; i < 4; ++i) {
    const int o = o0 + mB + i * 16 + qr4;
    const float4v bb = *(const float4v*)&bias[o];
#pragma unroll
    for (int j = 0; j < 4; ++j) {
      const int t = t0 + nB + j * 16 + col;
      float4v v = acc[i][j] + bb;
      if (relu) {
        v.x = fmaxf(v.x, 0.f); v.y = fmaxf(v.y, 0.f);
        v.z = fmaxf(v.z, 0.f); v.w = fmaxf(v.w, 0.f);
      }
      if (Res) {
        half4 r = *(const half4*)&Res[(size_t)(b * (T + 4) + t + 2) * Cout + o];
        v.x += (float)r.x; v.y += (float)r.y; v.z += (float)r.z; v.w += (float)r.w;
      }
      if (Yf) *(float4v*)&Yf[(size_t)(b * T + t) * Cout + o] = v;
      if (Yb) {
        half4 h;
        h.x = (f16)v.x; h.y = (f16)v.y; h.z = (f16)v.z; h.w = (f16)v.w;
        *(half4*)&Yb[(size_t)(b * (T + 4) + t + 2) * Cout + o] = h;
      }
    }
  }
}

// ---------------------------------------------------------------------------
// repack weights [L][O][I][5] f32 -> fragment-major f16:
// plane (l,kt): [(ci/32)][(o/16)][lane][8], lane supplies o=ob*16+(lane&15),
// ci = c32*32 + (lane>>4)*8 + e. Zero-padded for ci >= I.
__global__ void repack_w(const float* __restrict__ w,
                         f16* __restrict__ wp,
                         int O, int I, int Ip)
{
  const int lkt = blockIdx.y;
  const int l = lkt / 5, kt = lkt % 5;
  const float* wl = w + (size_t)l * O * I * 5;
  f16* wpl = wp + (size_t)lkt * O * Ip;
  const int OB = O >> 4;
  const int n = O * Ip;
  for (int m = blockIdx.x * 256 + threadIdx.x; m < n; m += gridDim.x * 256) {
    int e = m & 7, lane = (m >> 3) & 63, rest = m >> 9;
    int ob = rest % OB, c32 = rest / OB;
    int o  = ob * 16 + (lane & 15);
    int ci = c32 * 32 + ((lane >> 4) << 3) + e;
    float v = (ci < I) ? wl[((size_t)o * I + ci) * 5 + kt] : 0.f;
    wpl[m] = (f16)v;
  }
}

__global__ void cb_repack(const float* __restrict__ cb,  // [1024][256]
                          f16* __restrict__ wcb,          // frag-major -2c
                          float* __restrict__ cnorm)      // [1024] = |c|^2
{
  int o = blockIdx.x;
  int lane = threadIdx.x;  // 64
  float4v c = *(const float4v*)&cb[(size_t)o * 256 + lane * 4];
  float s = c.x * c.x + c.y * c.y + c.z * c.z + c.w * c.w;
  for (int off = 32; off > 0; off >>= 1) s += __shfl_down(s, off);
  if (lane == 0) cnorm[o] = s;
  // fragment-major scatter: OB = 64 (Cout=1024)
#pragma unroll
  for (int u = 0; u < 4; ++u) {
    int ci  = lane * 4 + u;
    int c32 = ci >> 5;
    int fl  = (o & 15) + (((ci >> 3) & 3) << 4);
    int e   = ci & 7;
    wcb[(((size_t)(c32 * 64 + (o >> 4)) << 6) + fl) * 8 + e] = (f16)(-2.f * c[u]);
  }
}

__global__ void mel_to_f16(const float* __restrict__ mel,  // [32][2048][80]
                           f16* __restrict__ out)           // [32][2052][96]
{
  int idx = blockIdx.x * 256 + threadIdx.x;
  if (idx >= 32 * 2052 * 12) return;
  int c8 = idx % 12;
  int r  = idx / 12;
  int tt = r % 2052;
  int b  = r / 2052;
  int t  = tt - 2;
  bool trow = (t >= 0) && (t < 2048);
  half8 hv;
#pragma unroll
  for (int e = 0; e < 8; ++e) {
    int m = c8 * 8 + e;
    float v = (trow && m < 80) ? mel[((size_t)b * 2048 + t) * 80 + m] : 0.f;
    hv[e] = (f16)v;
  }
  *(half8*)&out[((size_t)b * 2052 + tt) * 96 + c8 * 8] = hv;
}

__global__ void maxpool8(const f16* __restrict__ X,  // [32][2052][384]
                         f16* __restrict__ Y)         // [32][260][384]
{
  int idx = blockIdx.x * 256 + threadIdx.x;
  if (idx >= 32 * 256 * 48) return;
  int c8 = idx % 48;
  int r  = idx / 48;
  int tp = r % 256;
  int b  = r / 256;
  const f16* xp = &X[((size_t)b * 2052 + tp * 8 + 2) * 384 + c8 * 8];
  half8 m = *(const half8*)xp;
#pragma unroll
  for (int s = 1; s < 8; ++s) {
    half8 v = *(const half8*)(xp + (size_t)s * 384);
#pragma unroll
    for (int e = 0; e < 8; ++e) m[e] = (v[e] > m[e]) ? v[e] : m[e];
  }
  *(half8*)&Y[((size_t)b * 260 + tp + 2) * 384 + c8 * 8] = m;
}

__global__ void halo_zero(f16* a0, f16* a1, f16* b0, f16* b1, f16* zb,
                          float* accum)
{
  int bid = blockIdx.x;  // 5 bufs * 32 batches * 4 rows = 640
  if (bid == 0 && threadIdx.x == 0) { accum[0] = 0.f; accum[1] = 0.f; }
  int buf = bid >> 7;
  int r = bid & 127;
  int bb = r >> 2;
  int k = r & 3;
  f16* p; int T4, C;
  if      (buf == 0) { p = a0; T4 = 2052; C = 384; }
  else if (buf == 1) { p = a1; T4 = 2052; C = 384; }
  else if (buf == 2) { p = b0; T4 = 260;  C = 384; }
  else if (buf == 3) { p = b1; T4 = 260;  C = 384; }
  else               { p = zb; T4 = 260;  C = 256; }
  int tt = (k < 2) ? k : (T4 - 4 + k);
  f16* rowp = p + ((size_t)bb * T4 + tt) * C;
  for (int c = threadIdx.x; c < C; c += 256) rowp[c] = (f16)0.f;
}

__global__ void argmin_part(const float2* __restrict__ P,  // [8192][8]
                            int* __restrict__ outIdx)
{
  int row = blockIdx.x * 256 + threadIdx.x;
  if (row >= 8192) return;
  float bv = 3.4e38f;
  int bi = 0;
#pragma unroll
  for (int m = 0; m < 8; ++m) {
    float2 p = P[(size_t)row * 8 + m];
    int id = __float_as_int(p.y);
    if (p.x < bv || (p.x == bv && id < bi)) { bv = p.x; bi = id; }
  }
  outIdx[row] = bi;
}

__global__ void vq_gather(const float* __restrict__ zf,   // [8192][256]
                          const float* __restrict__ cb,   // [1024][256]
                          const int* __restrict__ idx,
                          float* __restrict__ zq,          // [8192][256]
                          float* __restrict__ accum)
{
  int row = blockIdx.x;
  int lane = threadIdx.x;  // 64
  int j = idx[row];
  float4v z = *(const float4v*)&zf[(size_t)row * 256 + lane * 4];
  float4v q = *(const float4v*)&cb[(size_t)j * 256 + lane * 4];
  *(float4v*)&zq[(size_t)row * 256 + lane * 4] = q;
  float4v d = z - q;
  float s = d.x * d.x + d.y * d.y + d.z * d.z + d.w * d.w;
  for (int off = 32; off > 0; off >>= 1) s += __shfl_down(s, off);
  if (lane == 0) atomicAdd(accum, s);
}

__global__ void finalize_loss(const float* __restrict__ accum,
                              float* __restrict__ out2)
{
  float c = accum[0] * (1.0f / 2097152.0f);  // mean over 32*256*256
  out2[0] = c;   // commit_loss
  out2[1] = c;   // vq_loss (== commit_loss numerically)
}

// ---------------------------------------------------------------------------
extern "C" void kernel_launch(void* const* d_in, const int* in_sizes, int n_in,
                              void* d_out, int out_size, void* d_ws, size_t ws_size,
                              hipStream_t stream)
{
  (void)in_sizes; (void)n_in; (void)out_size;
  const float* mel    = (const float*)d_in[0];
  const float* w_pre  = (const float*)d_in[1];
  const float* b_pre  = (const float*)d_in[2];
  const float* w_b1   = (const float*)d_in[3];
  const float* b_b1   = (const float*)d_in[4];
  const float* w_b2   = (const float*)d_in[5];
  const float* b_b2   = (const float*)d_in[6];
  const float* w_post = (const float*)d_in[7];
  const float* b_post = (const float*)d_in[8];
  const float* cbk    = (const float*)d_in[9];
  float* out = (float*)d_out;

  size_t off = 0;
  auto carve = [&](size_t bytes) -> char* {
    char* p = (char*)d_ws + off;
    off += (bytes + 255) & ~(size_t)255;
    return p;
  };
  f16*   wpPre  = (f16*)carve((size_t)5 * 384 * 96 * 2);
  f16*   wpB1   = (f16*)carve((size_t)6 * 5 * 384 * 384 * 2);
  f16*   wpB2   = (f16*)carve((size_t)6 * 5 * 384 * 384 * 2);
  f16*   wpPost = (f16*)carve((size_t)5 * 256 * 384 * 2);
  f16*   wpCb   = (f16*)carve((size_t)1024 * 256 * 2);
  float* cnorm  = (float*)carve(1024 * 4);
  float* accum  = (float*)carve(256);
  f16*   xmel   = (f16*)carve((size_t)32 * 2052 * 96 * 2);
  f16*   xa0    = (f16*)carve((size_t)32 * 2052 * 384 * 2);
  f16*   xa1    = (f16*)carve((size_t)32 * 2052 * 384 * 2);
  f16*   xb0    = (f16*)carve((size_t)32 * 260 * 384 * 2);
  f16*   xb1    = (f16*)carve((size_t)32 * 260 * 384 * 2);
  f16*   zeb    = (f16*)carve((size_t)32 * 260 * 256 * 2);
  float* zf     = (float*)carve((size_t)32 * 256 * 256 * 4);
  float2* part  = (float2*)carve((size_t)8192 * 8 * 8);
  int*   idxb   = (int*)carve((size_t)8192 * 4);
  carve(65536);  // guard
  if (off > ws_size) return;  // ~152 MB needed

  halo_zero<<<640, 256, 0, stream>>>(xa0, xa1, xb0, xb1, zeb, accum);
  repack_w<<<dim3(144, 5),  256, 0, stream>>>(w_pre,  wpPre,  384, 80,  96);
  repack_w<<<dim3(576, 30), 256, 0, stream>>>(w_b1,   wpB1,   384, 384, 384);
  repack_w<<<dim3(576, 30), 256, 0, stream>>>(w_b2,   wpB2,   384, 384, 384);
  repack_w<<<dim3(384, 5),  256, 0, stream>>>(w_post, wpPost, 256, 384, 384);
  cb_repack<<<1024, 64, 0, stream>>>(cbk, wpCb, cnorm);
  mel_to_f16<<<3078, 256, 0, stream>>>(mel, xmel);

  auto conv5 = [&](const f16* X, const f16* W, const float* bia, const f16* R,
                   float* YF, f16* YB, int Cinp, int Cout, int lgT, int relu) {
    dim3 g((32 << lgT) >> 7, Cout >> 7);
    conv_gemm<5><<<g, 256, 0, stream>>>(X, W, bia, R, YF, YB, nullptr,
                                        Cinp, Cout, lgT, 0, relu);
  };

  // pre-conv: relu(conv(mel))
  conv5(xmel, wpPre, b_pre, nullptr, nullptr, xa0, 96, 384, 11, 1);
  // stack 1 @ T=2048
  for (int i = 0; i < 6; ++i) {
    f16* in = (i & 1) ? xa1 : xa0;
    f16* o_ = (i & 1) ? xa0 : xa1;
    conv5(in, wpB1 + (size_t)i * 5 * 384 * 384, b_b1 + i * 384, in,
          nullptr, o_, 384, 384, 11, 1);
  }
  maxpool8<<<1536, 256, 0, stream>>>(xa0, xb0);
  // stack 2 @ T=256
  for (int i = 0; i < 6; ++i) {
    f16* in = (i & 1) ? xb1 : xb0;
    f16* o_ = (i & 1) ? xb0 : xb1;
    conv5(in, wpB2 + (size_t)i * 5 * 384 * 384, b_b2 + i * 384, in,
          nullptr, o_, 384, 384, 8, 1);
  }
  // post-conv: ze (f32 for loss, f16+halo for VQ scores)
  conv5(xb0, wpPost, b_post, nullptr, zf, zeb, 384, 256, 8, 0);
  // VQ scores: |c|^2 - 2 z.c as 1-tap "conv" (tapshift=2 = centered), with
  // fused per-block 128-bin argmin -> part[8192][8]
  {
    dim3 g((32 * 256) >> 7, 1024 >> 7);
    conv_gemm<1><<<g, 256, 0, stream>>>(zeb, wpCb, cnorm, nullptr, nullptr,
                                        nullptr, part, 256, 1024, 8, 2, 0);
  }

  argmin_part<<<32, 256, 0, stream>>>(part, idxb);
  vq_gather<<<8192, 64, 0, stream>>>(zf, cbk, idxb, out, accum);
  finalize_loss<<<1, 1, 0, stream>>>(accum, out + 2097152);
}

// Round 8
// 1174.395 us; speedup vs baseline: 1.6401x; 1.6401x over previous
//
#include <hip/hip_runtime.h>

// VQProsodyEncoder on gfx950: 13x conv1d(K=5) as implicit-GEMM f16 MFMA,
// maxpool(8), VQ via (-2*z.c + |c|^2) GEMM + fused partial argmin + gather.
// Activations: channel-last f16 [B][T+4][C] with 2-row zero halos.
// R9 = R7 (verified 112us big-conv) with ONE change: B's staging transport.
// R7 issued B via global_load_lds right before the __syncthreads vmcnt(0)
// drain -> ~900cy HBM/L3 exposure per c32. R9 prefetches B(n+1) into 3 named
// half8 regs (12 VGPR -- R8's 20-frag version spilled to scratch, +32MB
// WRITE_SIZE) during phase n, commits via 3 ds_write_b128 at phase n+1 top,
// and replaces the full drain with counted s_waitcnt vmcnt(3) (waits only
// L2-resident A; the 3 B loads stay in flight). B rows padded to 192 so all
// 4 waves issue exactly 3 B loads -> vmcnt(3) exact. LDS layout/read path
// byte-identical to R7 (0 bank conflicts). argmin_part folded into vq_gather.

typedef _Float16 f16;
typedef __attribute__((ext_vector_type(8))) _Float16 half8;
typedef __attribute__((ext_vector_type(4))) _Float16 half4;
typedef __attribute__((ext_vector_type(4))) float float4v;

__device__ __forceinline__ void async16(const void* g, void* l) {
  __builtin_amdgcn_global_load_lds(
      (const __attribute__((address_space(1))) void*)g,
      (__attribute__((address_space(3))) void*)l, 16, 0, 0);
}

// ---------------------------------------------------------------------------
// conv as implicit GEMM: Y[b,t,o] = sum_{kt,ci} W[kt][o][ci] * X[b][t+kt-2][ci]
// tile 128(M=o) x 128(N=b*t), BK=32, 4 waves 64x64, mfma_f32_16x16x32_f16.
// Wf is fragment-major: [NTAP][Cinp/32][Cout/16][64 lanes][8 f16].
template <int NTAP>
__global__ __launch_bounds__(256, 3) void conv_gemm(
    const f16* __restrict__ Xb,   // [B][T+4][Cinp], halo rows zeroed
    const f16* __restrict__ Wf,   // fragment-major weights
    const float* __restrict__ bias,  // [Cout]
    const f16* __restrict__ Res,  // [B][T+4][Cout] or null (residual add)
    float* __restrict__ Yf,       // [B][T][Cout] or null
    f16* __restrict__ Yb,         // [B][T+4][Cout] or null
    float2* __restrict__ Pmin,    // [N][gridDim.y] per-tile argmin or null
    int Cinp, int Cout, int lgT, int tapshift, int relu)
{
  __shared__ __align__(16) f16 Als[NTAP * 8 * 512];  // frag-major A: 8KB/tap
  __shared__ __align__(16) f16 Bls[192 * 32];        // 12KB; rows>=132 junk

  const int tid  = threadIdx.x;
  const int wave = tid >> 6;
  const int lane = tid & 63;
  const int T  = 1 << lgT;
  const int n0 = blockIdx.x << 7;
  const int o0 = blockIdx.y << 7;
  const int b  = n0 >> lgT;
  const int t0 = n0 & (T - 1);

  const int lane4 = lane >> 2;  // row-within-16 for B staging
  // B pre-swizzle (both-sides): physical slot (lane&3) of LDS row r*16+lane4
  // holds global slot (lane&3) ^ ((row>>1)&3) == (lane&3)^((lane>>3)&3).
  const int lkB = ((lane & 3) ^ ((lane >> 3) & 3)) << 3;

  const f16* gB0 = Xb + (size_t)(b * (T + 4) + t0) * Cinp + lkB;
  // per-wave B staging rounds r = wave, wave+4, wave+8 (rows r*16+lane4)
  const f16* gBr0 = gB0 + (size_t)((wave    ) * 16 + lane4) * Cinp;
  const f16* gBr1 = gB0 + (size_t)((wave + 4) * 16 + lane4) * Cinp;
  const f16* gBr2 = gB0 + (size_t)((wave + 8) * 16 + lane4) * Cinp;

  const int mB  = (wave & 1) * 64;
  const int nB  = (wave >> 1) * 64;
  const int r16 = lane & 15;
  const int g4  = lane >> 4;        // k-slot (8 f16) of this lane
  const int C32 = Cinp >> 5;
  const int OB  = Cout >> 4;
  const int fb  = (wave & 1) * 4;   // first A-frag within a tap's 8

  // fragment-major W: frag index (kt*C32+c32)*OB + ob, each frag 512 f16.
  const f16* gW = Wf + (((size_t)(o0 >> 4)) << 9) + lane * 8;

  float4v acc[4][4] = {};

  // prologue: B(0) -> regs (compiler waits on use)
  half8 breg0 = *(const half8*)(gBr0);
  half8 breg1 = *(const half8*)(gBr1);
  half8 breg2 = *(const half8*)(gBr2);

#pragma unroll 1
  for (int c32 = 0; c32 < C32; ++c32) {
    __builtin_amdgcn_s_barrier();       // WAR: prev phase's LDS reads done
    __builtin_amdgcn_sched_barrier(0);
    // commit B(c32) regs -> LDS (linear 16B/lane -> conflict-free)
    *(half8*)&Bls[(wave    ) * 512 + lane * 8] = breg0;
    *(half8*)&Bls[(wave + 4) * 512 + lane * 8] = breg1;
    *(half8*)&Bls[(wave + 8) * 512 + lane * 8] = breg2;
    // stage A: NTAP*8 frags of 1KB (frag-major, linear; L2-resident)
#pragma unroll
    for (int r = wave; r < NTAP * 8; r += 4) {
      const int kt = r >> 3, frag = r & 7;
      async16(gW + (((size_t)((kt * C32 + c32) * OB) + frag) << 9),
              &Als[r * 512 + lane * 8]);
    }
    __builtin_amdgcn_sched_barrier(0);  // pin issue order: A before B
    // prefetch B(c32+1) -> regs (HBM latency hides under this phase)
    const int cn = (c32 + 1 < C32) ? c32 + 1 : c32;  // clamp: keep count uniform
    breg0 = *(const half8*)(gBr0 + (cn << 5));
    breg1 = *(const half8*)(gBr1 + (cn << 5));
    breg2 = *(const half8*)(gBr2 + (cn << 5));
    // wait: all A staged (10 older) + ds_writes visible; 3 B stay in flight
    asm volatile("s_waitcnt vmcnt(3) lgkmcnt(0)" ::: "memory");
    __builtin_amdgcn_s_barrier();
    __builtin_amdgcn_sched_barrier(0);

#pragma unroll
    for (int kt = 0; kt < NTAP; ++kt) {
      half8 af[4], bv[4];
#pragma unroll
      for (int i = 0; i < 4; ++i)
        af[i] = *(const half8*)&Als[(kt * 8 + fb + i) * 512 + lane * 8];
#pragma unroll
      for (int j = 0; j < 4; ++j) {
        const int row = nB + j * 16 + r16 + tapshift + kt;
        const int sl  = g4 ^ ((row >> 1) & 3);
        bv[j] = *(const half8*)&Bls[row * 32 + sl * 8];
      }
      __builtin_amdgcn_s_setprio(1);
#pragma unroll
      for (int i = 0; i < 4; ++i)
#pragma unroll
        for (int j = 0; j < 4; ++j)
          acc[i][j] = __builtin_amdgcn_mfma_f32_16x16x32_f16(af[i], bv[j], acc[i][j], 0, 0, 0);
      __builtin_amdgcn_s_setprio(0);
    }
  }

  // epilogue: D[row][col]: col = lane&15, row = (lane>>4)*4 + reg
  const int col = lane & 15;
  const int qr4 = (lane >> 4) << 2;

  if (Pmin) {
    // VQ path: per-row argmin over this block's 128 bins (o0..o0+127).
    float bv[4] = {3.4e38f, 3.4e38f, 3.4e38f, 3.4e38f};
    int   bi[4] = {0, 0, 0, 0};
#pragma unroll
    for (int i = 0; i < 4; ++i) {
      const int o = o0 + mB + i * 16 + qr4;
      const float4v bb = *(const float4v*)&bias[o];  // |c|^2
#pragma unroll
      for (int j = 0; j < 4; ++j) {
        float4v v = acc[i][j] + bb;
#pragma unroll
        for (int r = 0; r < 4; ++r) {
          const float f = v[r];
          const int id = o + r;
          if (f < bv[j] || (f == bv[j] && id < bi[j])) { bv[j] = f; bi[j] = id; }
        }
      }
    }
#pragma unroll
    for (int off = 32; off >= 16; off >>= 1)
#pragma unroll
      for (int j = 0; j < 4; ++j) {
        const float ov = __shfl_down(bv[j], off);
        const int   oi = __shfl_down(bi[j], off);
        if (ov < bv[j] || (ov == bv[j] && oi < bi[j])) { bv[j] = ov; bi[j] = oi; }
      }
    __syncthreads();  // all waves done with LDS -> reuse Als for candidates
    float2* cand = (float2*)Als;  // [128 t][2 m-waves]
    if (lane < 16)
#pragma unroll
      for (int j = 0; j < 4; ++j)
        cand[(nB + j * 16 + lane) * 2 + (wave & 1)] =
            make_float2(bv[j], __int_as_float(bi[j]));
    __syncthreads();
    if (tid < 128) {
      float2 c0 = cand[tid * 2 + 0], c1 = cand[tid * 2 + 1];
      int i0 = __float_as_int(c0.x < c1.x ? c0.y : c1.y);
      float v0 = fminf(c0.x, c1.x);
      if (c0.x == c1.x) i0 = min(__float_as_int(c0.y), __float_as_int(c1.y));
      Pmin[(size_t)(n0 + tid) * gridDim.y + blockIdx.y] =
          make_float2(v0, __int_as_float(i0));
    }
    return;
  }

#pragma unroll
  for (int i = 0; i < 4; ++i) {
    const int o = o0 + mB + i * 16 + qr4;
    const float4v bb = *(const float4v*)&bias[o];
#pragma unroll
    for (int j = 0; j < 4; ++j) {
      const int t = t0 + nB + j * 16 + col;
      float4v v = acc[i][j] + bb;
      if (relu) {
        v.x = fmaxf(v.x, 0.f); v.y = fmaxf(v.y, 0.f);
        v.z = fmaxf(v.z, 0.f); v.w = fmaxf(v.w, 0.f);
      }
      if (Res) {
        half4 r = *(const half4*)&Res[(size_t)(b * (T + 4) + t + 2) * Cout + o];
        v.x += (float)r.x; v.y += (float)r.y; v.z += (float)r.z; v.w += (float)r.w;
      }
      if (Yf) *(float4v*)&Yf[(size_t)(b * T + t) * Cout + o] = v;
      if (Yb) {
        half4 h;
        h.x = (f16)v.x; h.y = (f16)v.y; h.z = (f16)v.z; h.w = (f16)v.w;
        *(half4*)&Yb[(size_t)(b * (T + 4) + t + 2) * Cout + o] = h;
      }
    }
  }
}

// ---------------------------------------------------------------------------
// repack weights [L][O][I][5] f32 -> fragment-major f16:
// plane (l,kt): [(ci/32)][(o/16)][lane][8], lane supplies o=ob*16+(lane&15),
// ci = c32*32 + (lane>>4)*8 + e. Zero-padded for ci >= I.
__global__ void repack_w(const float* __restrict__ w,
                         f16* __restrict__ wp,
                         int O, int I, int Ip)
{
  const int lkt = blockIdx.y;
  const int l = lkt / 5, kt = lkt % 5;
  const float* wl = w + (size_t)l * O * I * 5;
  f16* wpl = wp + (size_t)lkt * O * Ip;
  const int OB = O >> 4;
  const int n = O * Ip;
  for (int m = blockIdx.x * 256 + threadIdx.x; m < n; m += gridDim.x * 256) {
    int e = m & 7, lane = (m >> 3) & 63, rest = m >> 9;
    int ob = rest % OB, c32 = rest / OB;
    int o  = ob * 16 + (lane & 15);
    int ci = c32 * 32 + ((lane >> 4) << 3) + e;
    float v = (ci < I) ? wl[((size_t)o * I + ci) * 5 + kt] : 0.f;
    wpl[m] = (f16)v;
  }
}

__global__ void cb_repack(const float* __restrict__ cb,  // [1024][256]
                          f16* __restrict__ wcb,          // frag-major -2c
                          float* __restrict__ cnorm)      // [1024] = |c|^2
{
  int o = blockIdx.x;
  int lane = threadIdx.x;  // 64
  float4v c = *(const float4v*)&cb[(size_t)o * 256 + lane * 4];
  float s = c.x * c.x + c.y * c.y + c.z * c.z + c.w * c.w;
  for (int off = 32; off > 0; off >>= 1) s += __shfl_down(s, off);
  if (lane == 0) cnorm[o] = s;
  // fragment-major scatter: OB = 64 (Cout=1024)
#pragma unroll
  for (int u = 0; u < 4; ++u) {
    int ci  = lane * 4 + u;
    int c32 = ci >> 5;
    int fl  = (o & 15) + (((ci >> 3) & 3) << 4);
    int e   = ci & 7;
    wcb[(((size_t)(c32 * 64 + (o >> 4)) << 6) + fl) * 8 + e] = (f16)(-2.f * c[u]);
  }
}

__global__ void mel_to_f16(const float* __restrict__ mel,  // [32][2048][80]
                           f16* __restrict__ out)           // [32][2052][96]
{
  int idx = blockIdx.x * 256 + threadIdx.x;
  if (idx >= 32 * 2052 * 12) return;
  int c8 = idx % 12;
  int r  = idx / 12;
  int tt = r % 2052;
  int b  = r / 2052;
  int t  = tt - 2;
  bool trow = (t >= 0) && (t < 2048);
  half8 hv;
#pragma unroll
  for (int e = 0; e < 8; ++e) {
    int m = c8 * 8 + e;
    float v = (trow && m < 80) ? mel[((size_t)b * 2048 + t) * 80 + m] : 0.f;
    hv[e] = (f16)v;
  }
  *(half8*)&out[((size_t)b * 2052 + tt) * 96 + c8 * 8] = hv;
}

__global__ void maxpool8(const f16* __restrict__ X,  // [32][2052][384]
                         f16* __restrict__ Y)         // [32][260][384]
{
  int idx = blockIdx.x * 256 + threadIdx.x;
  if (idx >= 32 * 256 * 48) return;
  int c8 = idx % 48;
  int r  = idx / 48;
  int tp = r % 256;
  int b  = r / 256;
  const f16* xp = &X[((size_t)b * 2052 + tp * 8 + 2) * 384 + c8 * 8];
  half8 m = *(const half8*)xp;
#pragma unroll
  for (int s = 1; s < 8; ++s) {
    half8 v = *(const half8*)(xp + (size_t)s * 384);
#pragma unroll
    for (int e = 0; e < 8; ++e) m[e] = (v[e] > m[e]) ? v[e] : m[e];
  }
  *(half8*)&Y[((size_t)b * 260 + tp + 2) * 384 + c8 * 8] = m;
}

__global__ void halo_zero(f16* a0, f16* a1, f16* b0, f16* b1, f16* zb,
                          float* accum)
{
  int bid = blockIdx.x;  // 5 bufs * 32 batches * 4 rows = 640
  if (bid == 0 && threadIdx.x == 0) { accum[0] = 0.f; accum[1] = 0.f; }
  int buf = bid >> 7;
  int r = bid & 127;
  int bb = r >> 2;
  int k = r & 3;
  f16* p; int T4, C;
  if      (buf == 0) { p = a0; T4 = 2052; C = 384; }
  else if (buf == 1) { p = a1; T4 = 2052; C = 384; }
  else if (buf == 2) { p = b0; T4 = 260;  C = 384; }
  else if (buf == 3) { p = b1; T4 = 260;  C = 384; }
  else               { p = zb; T4 = 260;  C = 256; }
  int tt = (k < 2) ? k : (T4 - 4 + k);
  f16* rowp = p + ((size_t)bb * T4 + tt) * C;
  for (int c = threadIdx.x; c < C; c += 256) rowp[c] = (f16)0.f;
}

__global__ void vq_gather(const float* __restrict__ zf,   // [8192][256]
                          const float* __restrict__ cb,   // [1024][256]
                          const float2* __restrict__ P,   // [8192][8] partials
                          float* __restrict__ zq,          // [8192][256]
                          float* __restrict__ accum)
{
  int row = blockIdx.x;
  int lane = threadIdx.x;  // 64
  // fold the 8-tile argmin reduce in here (was argmin_part kernel)
  float bv = 3.4e38f;
  int j = 0;
#pragma unroll
  for (int m = 0; m < 8; ++m) {
    float2 p = P[(size_t)row * 8 + m];
    int id = __float_as_int(p.y);
    if (p.x < bv || (p.x == bv && id < j)) { bv = p.x; j = id; }
  }
  float4v z = *(const float4v*)&zf[(size_t)row * 256 + lane * 4];
  float4v q = *(const float4v*)&cb[(size_t)j * 256 + lane * 4];
  *(float4v*)&zq[(size_t)row * 256 + lane * 4] = q;
  float4v d = z - q;
  float s = d.x * d.x + d.y * d.y + d.z * d.z + d.w * d.w;
  for (int off = 32; off > 0; off >>= 1) s += __shfl_down(s, off);
  if (lane == 0) atomicAdd(accum, s);
}

__global__ void finalize_loss(const float* __restrict__ accum,
                              float* __restrict__ out2)
{
  float c = accum[0] * (1.0f / 2097152.0f);  // mean over 32*256*256
  out2[0] = c;   // commit_loss
  out2[1] = c;   // vq_loss (== commit_loss numerically)
}

// ---------------------------------------------------------------------------
extern "C" void kernel_launch(void* const* d_in, const int* in_sizes, int n_in,
                              void* d_out, int out_size, void* d_ws, size_t ws_size,
                              hipStream_t stream)
{
  (void)in_sizes; (void)n_in; (void)out_size;
  const float* mel    = (const float*)d_in[0];
  const float* w_pre  = (const float*)d_in[1];
  const float* b_pre  = (const float*)d_in[2];
  const float* w_b1   = (const float*)d_in[3];
  const float* b_b1   = (const float*)d_in[4];
  const float* w_b2   = (const float*)d_in[5];
  const float* b_b2   = (const float*)d_in[6];
  const float* w_post = (const float*)d_in[7];
  const float* b_post = (const float*)d_in[8];
  const float* cbk    = (const float*)d_in[9];
  float* out = (float*)d_out;

  size_t off = 0;
  auto carve = [&](size_t bytes) -> char* {
    char* p = (char*)d_ws + off;
    off += (bytes + 255) & ~(size_t)255;
    return p;
  };
  f16*   wpPre  = (f16*)carve((size_t)5 * 384 * 96 * 2);
  f16*   wpB1   = (f16*)carve((size_t)6 * 5 * 384 * 384 * 2);
  f16*   wpB2   = (f16*)carve((size_t)6 * 5 * 384 * 384 * 2);
  f16*   wpPost = (f16*)carve((size_t)5 * 256 * 384 * 2);
  f16*   wpCb   = (f16*)carve((size_t)1024 * 256 * 2);
  float* cnorm  = (float*)carve(1024 * 4);
  float* accum  = (float*)carve(256);
  f16*   xmel   = (f16*)carve((size_t)32 * 2052 * 96 * 2);
  f16*   xa0    = (f16*)carve((size_t)32 * 2052 * 384 * 2);
  f16*   xa1    = (f16*)carve((size_t)32 * 2052 * 384 * 2);
  f16*   xb0    = (f16*)carve((size_t)32 * 260 * 384 * 2);
  f16*   xb1    = (f16*)carve((size_t)32 * 260 * 384 * 2);
  f16*   zeb    = (f16*)carve((size_t)32 * 260 * 256 * 2);
  float* zf     = (float*)carve((size_t)32 * 256 * 256 * 4);
  float2* part  = (float2*)carve((size_t)8192 * 8 * 8);
  carve(131072);  // guard: B staging over-reads up to ~60 rows past buffers
  if (off > ws_size) return;  // ~152 MB needed

  halo_zero<<<640, 256, 0, stream>>>(xa0, xa1, xb0, xb1, zeb, accum);
  repack_w<<<dim3(144, 5),  256, 0, stream>>>(w_pre,  wpPre,  384, 80,  96);
  repack_w<<<dim3(576, 30), 256, 0, stream>>>(w_b1,   wpB1,   384, 384, 384);
  repack_w<<<dim3(576, 30), 256, 0, stream>>>(w_b2,   wpB2,   384, 384, 384);
  repack_w<<<dim3(384, 5),  256, 0, stream>>>(w_post, wpPost, 256, 384, 384);
  cb_repack<<<1024, 64, 0, stream>>>(cbk, wpCb, cnorm);
  mel_to_f16<<<3078, 256, 0, stream>>>(mel, xmel);

  auto conv5 = [&](const f16* X, const f16* W, const float* bia, const f16* R,
                   float* YF, f16* YB, int Cinp, int Cout, int lgT, int relu) {
    dim3 g((32 << lgT) >> 7, Cout >> 7);
    conv_gemm<5><<<g, 256, 0, stream>>>(X, W, bia, R, YF, YB, nullptr,
                                        Cinp, Cout, lgT, 0, relu);
  };

  // pre-conv: relu(conv(mel))
  conv5(xmel, wpPre, b_pre, nullptr, nullptr, xa0, 96, 384, 11, 1);
  // stack 1 @ T=2048
  for (int i = 0; i < 6; ++i) {
    f16* in = (i & 1) ? xa1 : xa0;
    f16* o_ = (i & 1) ? xa0 : xa1;
    conv5(in, wpB1 + (size_t)i * 5 * 384 * 384, b_b1 + i * 384, in,
          nullptr, o_, 384, 384, 11, 1);
  }
  maxpool8<<<1536, 256, 0, stream>>>(xa0, xb0);
  // stack 2 @ T=256
  for (int i = 0; i < 6; ++i) {
    f16* in = (i & 1) ? xb1 : xb0;
    f16* o_ = (i & 1) ? xb0 : xb1;
    conv5(in, wpB2 + (size_t)i * 5 * 384 * 384, b_b2 + i * 384, in,
          nullptr, o_, 384, 384, 8, 1);
  }
  // post-conv: ze (f32 for loss, f16+halo for VQ scores)
  conv5(xb0, wpPost, b_post, nullptr, zf, zeb, 384, 256, 8, 0);
  // VQ scores: |c|^2 - 2 z.c as 1-tap "conv" (tapshift=2 = centered), with
  // fused per-block 128-bin argmin -> part[8192][8]
  {
    dim3 g((32 * 256) >> 7, 1024 >> 7);
    conv_gemm<1><<<g, 256, 0, stream>>>(zeb, wpCb, cnorm, nullptr, nullptr,
                                        nullptr, part, 256, 1024, 8, 2, 0);
  }

  vq_gather<<<8192, 64, 0, stream>>>(zf, cbk, part, out, accum);
  finalize_loss<<<1, 1, 0, stream>>>(accum, out + 2097152);
}

// Round 9
// 1161.064 us; speedup vs baseline: 1.6589x; 1.0115x over previous
//
#include <hip/hip_runtime.h>

// VQProsodyEncoder on gfx950: 13x conv1d(K=5) as implicit-GEMM f16 MFMA,
// maxpool(8), VQ via (-2*z.c + |c|^2) GEMM + fused partial argmin + gather.
// Activations: channel-last f16 [B][T+4][C] with 2-row zero halos.
// R10 = R7's verified conv_gemm (112us big-conv: 128x128 tile, frag-major A
// in LDS via global_load_lds, XOR-swizzled B, 0 bank conflicts, fused VQ
// argmin; R9's reg-staged B reverted -- it added +33% B fetch for no gain)
// + rewritten repack_w: old version read stride-20B gathers once per kt-plane
// (~5x HBM re-fetch of each weight tensor, est. 50-120us each for B1/B2).
// New version: one thread per (o, ci-octet) reads 160B fully coalesced ONCE,
// scatters one half8 per tap plane. + vq_gather with folded argmin (R9).

typedef _Float16 f16;
typedef __attribute__((ext_vector_type(8))) _Float16 half8;
typedef __attribute__((ext_vector_type(4))) _Float16 half4;
typedef __attribute__((ext_vector_type(4))) float float4v;

__device__ __forceinline__ void async16(const void* g, void* l) {
  __builtin_amdgcn_global_load_lds(
      (const __attribute__((address_space(1))) void*)g,
      (__attribute__((address_space(3))) void*)l, 16, 0, 0);
}

// ---------------------------------------------------------------------------
// conv as implicit GEMM: Y[b,t,o] = sum_{kt,ci} W[kt][o][ci] * X[b][t+kt-2][ci]
// tile 128(M=o) x 128(N=b*t), BK=32, 4 waves 64x64, mfma_f32_16x16x32_f16.
// Wf is fragment-major: [NTAP][Cinp/32][Cout/16][64 lanes][8 f16].
template <int NTAP>
__global__ __launch_bounds__(256, 3) void conv_gemm(
    const f16* __restrict__ Xb,   // [B][T+4][Cinp], halo rows zeroed
    const f16* __restrict__ Wf,   // fragment-major weights
    const float* __restrict__ bias,  // [Cout]
    const f16* __restrict__ Res,  // [B][T+4][Cout] or null (residual add)
    float* __restrict__ Yf,       // [B][T][Cout] or null
    f16* __restrict__ Yb,         // [B][T+4][Cout] or null
    float2* __restrict__ Pmin,    // [N][gridDim.y] per-tile argmin or null
    int Cinp, int Cout, int lgT, int tapshift, int relu)
{
  __shared__ __align__(16) f16 Als[NTAP * 8 * 512];  // frag-major A: 8KB/tap
  __shared__ __align__(16) f16 Bls[144 * 32];        // 144 t-rows x 32 ci

  const int tid  = threadIdx.x;
  const int wave = tid >> 6;
  const int lane = tid & 63;
  const int T  = 1 << lgT;
  const int n0 = blockIdx.x << 7;
  const int o0 = blockIdx.y << 7;
  const int b  = n0 >> lgT;
  const int t0 = n0 & (T - 1);

  const int lane4 = lane >> 2;  // row-within-16 for B staging
  // B pre-swizzle (both-sides): physical slot (lane&3) of LDS row r*16+lane4
  // holds global slot (lane&3) ^ ((row>>1)&3) == (lane&3)^((lane>>3)&3).
  const int lkB = ((lane & 3) ^ ((lane >> 3) & 3)) << 3;

  const f16* gB0 = Xb + (size_t)(b * (T + 4) + t0) * Cinp + lkB;

  const int mB  = (wave & 1) * 64;
  const int nB  = (wave >> 1) * 64;
  const int r16 = lane & 15;
  const int g4  = lane >> 4;        // k-slot (8 f16) of this lane
  const int C32 = Cinp >> 5;
  const int OB  = Cout >> 4;
  const int fb  = (wave & 1) * 4;   // first A-frag within a tap's 8

  // fragment-major W: frag index (kt*C32+c32)*OB + ob, each frag 512 f16.
  const f16* gW = Wf + (((size_t)(o0 >> 4)) << 9) + lane * 8;

  float4v acc[4][4] = {};

#pragma unroll 1
  for (int c32 = 0; c32 < C32; ++c32) {
    __syncthreads();  // previous iteration's LDS reads complete
    // stage A: NTAP*8 frags of 1KB (frag-major, linear -> conflict-free)
#pragma unroll
    for (int r = wave; r < NTAP * 8; r += 4) {
      const int kt = r >> 3, frag = r & 7;
      async16(gW + (((size_t)((kt * C32 + c32) * OB) + frag) << 9),
              &Als[r * 512 + lane * 8]);
    }
    // stage B: 9 wave-rounds = 144 t-rows (rows >=132 junk, never read)
    for (int r = wave; r < 9; r += 4)
      async16(gB0 + (size_t)(r * 16 + lane4) * Cinp + (c32 << 5),
              &Bls[r * 512 + lane * 8]);
    __syncthreads();  // drains vmcnt: staging visible

#pragma unroll
    for (int kt = 0; kt < NTAP; ++kt) {
      half8 af[4], bv[4];
#pragma unroll
      for (int i = 0; i < 4; ++i)
        af[i] = *(const half8*)&Als[(kt * 8 + fb + i) * 512 + lane * 8];
#pragma unroll
      for (int j = 0; j < 4; ++j) {
        const int row = nB + j * 16 + r16 + tapshift + kt;
        const int sl  = g4 ^ ((row >> 1) & 3);
        bv[j] = *(const half8*)&Bls[row * 32 + sl * 8];
      }
      __builtin_amdgcn_s_setprio(1);
#pragma unroll
      for (int i = 0; i < 4; ++i)
#pragma unroll
        for (int j = 0; j < 4; ++j)
          acc[i][j] = __builtin_amdgcn_mfma_f32_16x16x32_f16(af[i], bv[j], acc[i][j], 0, 0, 0);
      __builtin_amdgcn_s_setprio(0);
    }
  }

  // epilogue: D[row][col]: col = lane&15, row = (lane>>4)*4 + reg
  const int col = lane & 15;
  const int qr4 = (lane >> 4) << 2;

  if (Pmin) {
    // VQ path: per-row argmin over this block's 128 bins (o0..o0+127).
    float bv[4] = {3.4e38f, 3.4e38f, 3.4e38f, 3.4e38f};
    int   bi[4] = {0, 0, 0, 0};
#pragma unroll
    for (int i = 0; i < 4; ++i) {
      const int o = o0 + mB + i * 16 + qr4;
      const float4v bb = *(const float4v*)&bias[o];  // |c|^2
#pragma unroll
      for (int j = 0; j < 4; ++j) {
        float4v v = acc[i][j] + bb;
#pragma unroll
        for (int r = 0; r < 4; ++r) {
          const float f = v[r];
          const int id = o + r;
          if (f < bv[j] || (f == bv[j] && id < bi[j])) { bv[j] = f; bi[j] = id; }
        }
      }
    }
#pragma unroll
    for (int off = 32; off >= 16; off >>= 1)
#pragma unroll
      for (int j = 0; j < 4; ++j) {
        const float ov = __shfl_down(bv[j], off);
        const int   oi = __shfl_down(bi[j], off);
        if (ov < bv[j] || (ov == bv[j] && oi < bi[j])) { bv[j] = ov; bi[j] = oi; }
      }
    __syncthreads();  // all waves done with LDS -> reuse Als for candidates
    float2* cand = (float2*)Als;  // [128 t][2 m-waves]
    if (lane < 16)
#pragma unroll
      for (int j = 0; j < 4; ++j)
        cand[(nB + j * 16 + lane) * 2 + (wave & 1)] =
            make_float2(bv[j], __int_as_float(bi[j]));
    __syncthreads();
    if (tid < 128) {
      float2 c0 = cand[tid * 2 + 0], c1 = cand[tid * 2 + 1];
      int i0 = __float_as_int(c0.x < c1.x ? c0.y : c1.y);
      float v0 = fminf(c0.x, c1.x);
      if (c0.x == c1.x) i0 = min(__float_as_int(c0.y), __float_as_int(c1.y));
      Pmin[(size_t)(n0 + tid) * gridDim.y + blockIdx.y] =
          make_float2(v0, __int_as_float(i0));
    }
    return;
  }

#pragma unroll
  for (int i = 0; i < 4; ++i) {
    const int o = o0 + mB + i * 16 + qr4;
    const float4v bb = *(const float4v*)&bias[o];
#pragma unroll
    for (int j = 0; j < 4; ++j) {
      const int t = t0 + nB + j * 16 + col;
      float4v v = acc[i][j] + bb;
      if (relu) {
        v.x = fmaxf(v.x, 0.f); v.y = fmaxf(v.y, 0.f);
        v.z = fmaxf(v.z, 0.f); v.w = fmaxf(v.w, 0.f);
      }
      if (Res) {
        half4 r = *(const half4*)&Res[(size_t)(b * (T + 4) + t + 2) * Cout + o];
        v.x += (float)r.x; v.y += (float)r.y; v.z += (float)r.z; v.w += (float)r.w;
      }
      if (Yf) *(float4v*)&Yf[(size_t)(b * T + t) * Cout + o] = v;
      if (Yb) {
        half4 h;
        h.x = (f16)v.x; h.y = (f16)v.y; h.z = (f16)v.z; h.w = (f16)v.w;
        *(half4*)&Yb[(size_t)(b * (T + 4) + t + 2) * Cout + o] = h;
      }
    }
  }
}

// ---------------------------------------------------------------------------
// repack weights [L][O][I][5] f32 -> fragment-major f16 [L][5][O][Ip].
// One thread per (o, ci-octet): the 5 taps of consecutive (o,ci) are
// CONTIGUOUS in the source, so each thread reads 160B coalesced exactly once
// (old version gathered stride-20B once per kt-plane -> ~5x HBM re-fetch)
// and writes one half8 into each of the 5 fragment-major tap planes.
__global__ void repack_w(const float* __restrict__ w,
                         f16* __restrict__ wp,
                         int O, int I, int Ip)
{
  const int l = blockIdx.y;
  const int C8 = Ip >> 3;
  const int n = O * C8;
  const float* wl = w + (size_t)l * O * I * 5;
  f16* wpl = wp + (size_t)l * 5 * O * Ip;
  const int OB = O >> 4;
  for (int e = blockIdx.x * 256 + threadIdx.x; e < n; e += gridDim.x * 256) {
    const int o = e / C8, c8 = e - o * C8;
    const int ci0 = c8 << 3;
    // frag-major addr (f16 units): ((c32*OB + o/16)*64 + (o&15 | g<<4))*8 + sub
    const size_t base = ((((size_t)(ci0 >> 5) * OB + (o >> 4)) << 6)
                         + ((o & 15) | ((c8 & 3) << 4))) << 3;
    half8 hv[5];
#pragma unroll
    for (int kt = 0; kt < 5; ++kt)
#pragma unroll
      for (int u = 0; u < 8; ++u) hv[kt][u] = (f16)0.f;
    const int lim = (I - ci0 < 8) ? (I - ci0) : 8;
    for (int u = 0; u < lim; ++u) {
      const float* src = wl + ((size_t)o * I + ci0 + u) * 5;
#pragma unroll
      for (int kt = 0; kt < 5; ++kt) hv[kt][u] = (f16)src[kt];
    }
#pragma unroll
    for (int kt = 0; kt < 5; ++kt)
      *(half8*)&wpl[(size_t)kt * O * Ip + base] = hv[kt];
  }
}

__global__ void cb_repack(const float* __restrict__ cb,  // [1024][256]
                          f16* __restrict__ wcb,          // frag-major -2c
                          float* __restrict__ cnorm)      // [1024] = |c|^2
{
  int o = blockIdx.x;
  int lane = threadIdx.x;  // 64
  float4v c = *(const float4v*)&cb[(size_t)o * 256 + lane * 4];
  float s = c.x * c.x + c.y * c.y + c.z * c.z + c.w * c.w;
  for (int off = 32; off > 0; off >>= 1) s += __shfl_down(s, off);
  if (lane == 0) cnorm[o] = s;
  // fragment-major scatter: OB = 64 (Cout=1024)
#pragma unroll
  for (int u = 0; u < 4; ++u) {
    int ci  = lane * 4 + u;
    int c32 = ci >> 5;
    int fl  = (o & 15) + (((ci >> 3) & 3) << 4);
    int e   = ci & 7;
    wcb[(((size_t)(c32 * 64 + (o >> 4)) << 6) + fl) * 8 + e] = (f16)(-2.f * c[u]);
  }
}

__global__ void mel_to_f16(const float* __restrict__ mel,  // [32][2048][80]
                           f16* __restrict__ out)           // [32][2052][96]
{
  int idx = blockIdx.x * 256 + threadIdx.x;
  if (idx >= 32 * 2052 * 12) return;
  int c8 = idx % 12;
  int r  = idx / 12;
  int tt = r % 2052;
  int b  = r / 2052;
  int t  = tt - 2;
  bool trow = (t >= 0) && (t < 2048);
  half8 hv;
#pragma unroll
  for (int e = 0; e < 8; ++e) {
    int m = c8 * 8 + e;
    float v = (trow && m < 80) ? mel[((size_t)b * 2048 + t) * 80 + m] : 0.f;
    hv[e] = (f16)v;
  }
  *(half8*)&out[((size_t)b * 2052 + tt) * 96 + c8 * 8] = hv;
}

__global__ void maxpool8(const f16* __restrict__ X,  // [32][2052][384]
                         f16* __restrict__ Y)         // [32][260][384]
{
  int idx = blockIdx.x * 256 + threadIdx.x;
  if (idx >= 32 * 256 * 48) return;
  int c8 = idx % 48;
  int r  = idx / 48;
  int tp = r % 256;
  int b  = r / 256;
  const f16* xp = &X[((size_t)b * 2052 + tp * 8 + 2) * 384 + c8 * 8];
  half8 m = *(const half8*)xp;
#pragma unroll
  for (int s = 1; s < 8; ++s) {
    half8 v = *(const half8*)(xp + (size_t)s * 384);
#pragma unroll
    for (int e = 0; e < 8; ++e) m[e] = (v[e] > m[e]) ? v[e] : m[e];
  }
  *(half8*)&Y[((size_t)b * 260 + tp + 2) * 384 + c8 * 8] = m;
}

__global__ void halo_zero(f16* a0, f16* a1, f16* b0, f16* b1, f16* zb,
                          float* accum)
{
  int bid = blockIdx.x;  // 5 bufs * 32 batches * 4 rows = 640
  if (bid == 0 && threadIdx.x == 0) { accum[0] = 0.f; accum[1] = 0.f; }
  int buf = bid >> 7;
  int r = bid & 127;
  int bb = r >> 2;
  int k = r & 3;
  f16* p; int T4, C;
  if      (buf == 0) { p = a0; T4 = 2052; C = 384; }
  else if (buf == 1) { p = a1; T4 = 2052; C = 384; }
  else if (buf == 2) { p = b0; T4 = 260;  C = 384; }
  else if (buf == 3) { p = b1; T4 = 260;  C = 384; }
  else               { p = zb; T4 = 260;  C = 256; }
  int tt = (k < 2) ? k : (T4 - 4 + k);
  f16* rowp = p + ((size_t)bb * T4 + tt) * C;
  for (int c = threadIdx.x; c < C; c += 256) rowp[c] = (f16)0.f;
}

__global__ void vq_gather(const float* __restrict__ zf,   // [8192][256]
                          const float* __restrict__ cb,   // [1024][256]
                          const float2* __restrict__ P,   // [8192][8] partials
                          float* __restrict__ zq,          // [8192][256]
                          float* __restrict__ accum)
{
  int row = blockIdx.x;
  int lane = threadIdx.x;  // 64
  // fold the 8-tile argmin reduce in here (was argmin_part kernel)
  float bv = 3.4e38f;
  int j = 0;
#pragma unroll
  for (int m = 0; m < 8; ++m) {
    float2 p = P[(size_t)row * 8 + m];
    int id = __float_as_int(p.y);
    if (p.x < bv || (p.x == bv && id < j)) { bv = p.x; j = id; }
  }
  float4v z = *(const float4v*)&zf[(size_t)row * 256 + lane * 4];
  float4v q = *(const float4v*)&cb[(size_t)j * 256 + lane * 4];
  *(float4v*)&zq[(size_t)row * 256 + lane * 4] = q;
  float4v d = z - q;
  float s = d.x * d.x + d.y * d.y + d.z * d.z + d.w * d.w;
  for (int off = 32; off > 0; off >>= 1) s += __shfl_down(s, off);
  if (lane == 0) atomicAdd(accum, s);
}

__global__ void finalize_loss(const float* __restrict__ accum,
                              float* __restrict__ out2)
{
  float c = accum[0] * (1.0f / 2097152.0f);  // mean over 32*256*256
  out2[0] = c;   // commit_loss
  out2[1] = c;   // vq_loss (== commit_loss numerically)
}

// ---------------------------------------------------------------------------
extern "C" void kernel_launch(void* const* d_in, const int* in_sizes, int n_in,
                              void* d_out, int out_size, void* d_ws, size_t ws_size,
                              hipStream_t stream)
{
  (void)in_sizes; (void)n_in; (void)out_size;
  const float* mel    = (const float*)d_in[0];
  const float* w_pre  = (const float*)d_in[1];
  const float* b_pre  = (const float*)d_in[2];
  const float* w_b1   = (const float*)d_in[3];
  const float* b_b1   = (const float*)d_in[4];
  const float* w_b2   = (const float*)d_in[5];
  const float* b_b2   = (const float*)d_in[6];
  const float* w_post = (const float*)d_in[7];
  const float* b_post = (const float*)d_in[8];
  const float* cbk    = (const float*)d_in[9];
  float* out = (float*)d_out;

  size_t off = 0;
  auto carve = [&](size_t bytes) -> char* {
    char* p = (char*)d_ws + off;
    off += (bytes + 255) & ~(size_t)255;
    return p;
  };
  f16*   wpPre  = (f16*)carve((size_t)5 * 384 * 96 * 2);
  f16*   wpB1   = (f16*)carve((size_t)6 * 5 * 384 * 384 * 2);
  f16*   wpB2   = (f16*)carve((size_t)6 * 5 * 384 * 384 * 2);
  f16*   wpPost = (f16*)carve((size_t)5 * 256 * 384 * 2);
  f16*   wpCb   = (f16*)carve((size_t)1024 * 256 * 2);
  float* cnorm  = (float*)carve(1024 * 4);
  float* accum  = (float*)carve(256);
  f16*   xmel   = (f16*)carve((size_t)32 * 2052 * 96 * 2);
  f16*   xa0    = (f16*)carve((size_t)32 * 2052 * 384 * 2);
  f16*   xa1    = (f16*)carve((size_t)32 * 2052 * 384 * 2);
  f16*   xb0    = (f16*)carve((size_t)32 * 260 * 384 * 2);
  f16*   xb1    = (f16*)carve((size_t)32 * 260 * 384 * 2);
  f16*   zeb    = (f16*)carve((size_t)32 * 260 * 256 * 2);
  float* zf     = (float*)carve((size_t)32 * 256 * 256 * 4);
  float2* part  = (float2*)carve((size_t)8192 * 8 * 8);
  carve(131072);  // guard: B staging over-reads past last buffer
  if (off > ws_size) return;  // ~152 MB needed

  halo_zero<<<640, 256, 0, stream>>>(xa0, xa1, xb0, xb1, zeb, accum);
  // repack: one thread per (o, ci-octet); grid.y = layers
  repack_w<<<dim3(18, 1), 256, 0, stream>>>(w_pre,  wpPre,  384, 80,  96);
  repack_w<<<dim3(72, 6), 256, 0, stream>>>(w_b1,   wpB1,   384, 384, 384);
  repack_w<<<dim3(72, 6), 256, 0, stream>>>(w_b2,   wpB2,   384, 384, 384);
  repack_w<<<dim3(48, 1), 256, 0, stream>>>(w_post, wpPost, 256, 384, 384);
  cb_repack<<<1024, 64, 0, stream>>>(cbk, wpCb, cnorm);
  mel_to_f16<<<3078, 256, 0, stream>>>(mel, xmel);

  auto conv5 = [&](const f16* X, const f16* W, const float* bia, const f16* R,
                   float* YF, f16* YB, int Cinp, int Cout, int lgT, int relu) {
    dim3 g((32 << lgT) >> 7, Cout >> 7);
    conv_gemm<5><<<g, 256, 0, stream>>>(X, W, bia, R, YF, YB, nullptr,
                                        Cinp, Cout, lgT, 0, relu);
  };

  // pre-conv: relu(conv(mel))
  conv5(xmel, wpPre, b_pre, nullptr, nullptr, xa0, 96, 384, 11, 1);
  // stack 1 @ T=2048
  for (int i = 0; i < 6; ++i) {
    f16* in = (i & 1) ? xa1 : xa0;
    f16* o_ = (i & 1) ? xa0 : xa1;
    conv5(in, wpB1 + (size_t)i * 5 * 384 * 384, b_b1 + i * 384, in,
          nullptr, o_, 384, 384, 11, 1);
  }
  maxpool8<<<1536, 256, 0, stream>>>(xa0, xb0);
  // stack 2 @ T=256
  for (int i = 0; i < 6; ++i) {
    f16* in = (i & 1) ? xb1 : xb0;
    f16* o_ = (i & 1) ? xb0 : xb1;
    conv5(in, wpB2 + (size_t)i * 5 * 384 * 384, b_b2 + i * 384, in,
          nullptr, o_, 384, 384, 8, 1);
  }
  // post-conv: ze (f32 for loss, f16+halo for VQ scores)
  conv5(xb0, wpPost, b_post, nullptr, zf, zeb, 384, 256, 8, 0);
  // VQ scores: |c|^2 - 2 z.c as 1-tap "conv" (tapshift=2 = centered), with
  // fused per-block 128-bin argmin -> part[8192][8]
  {
    dim3 g((32 * 256) >> 7, 1024 >> 7);
    conv_gemm<1><<<g, 256, 0, stream>>>(zeb, wpCb, cnorm, nullptr, nullptr,
                                        nullptr, part, 256, 1024, 8, 2, 0);
  }

  vq_gather<<<8192, 64, 0, stream>>>(zf, cbk, part, out, accum);
  finalize_loss<<<1, 1, 0, stream>>>(accum, out + 2097152);
}